// Round 3
// baseline (347.469 us; speedup 1.0000x reference)
//
#include <hip/hip_runtime.h>

#define BDIM 2
#define SEQ  1568
#define DIM  768
#define NH   12
#define FR   8
#define NTOK 196
#define HD   64
#define MTOT (BDIM*SEQ)   // 3136 token rows
#define M2   (MTOT*FR)    // 25088 (t,f) rows

typedef __attribute__((ext_vector_type(8))) short s16x8;
typedef __attribute__((ext_vector_type(4))) float f32x4;
typedef __attribute__((ext_vector_type(16))) float f32x16;
typedef __attribute__((ext_vector_type(4))) int i32x4;

static __device__ __forceinline__ float bf2f(ushort u) {
  return __uint_as_float(((unsigned)u) << 16);
}
static __device__ __forceinline__ ushort f2bf(float f) {
  unsigned u = __float_as_uint(f);
  unsigned r = (u + 0x7fffu + ((u >> 16) & 1u)) >> 16;
  return (ushort)r;
}
static __device__ __forceinline__ f32x4 mfma16(s16x8 a, s16x8 b, f32x4 c) {
  return __builtin_amdgcn_mfma_f32_16x16x32_bf16(a, b, c, 0, 0, 0);
}
static __device__ __forceinline__ f32x16 mfma32(s16x8 a, s16x8 b, f32x16 c) {
  return __builtin_amdgcn_mfma_f32_32x32x16_bf16(a, b, c, 0, 0, 0);
}
static __device__ __forceinline__ int cvtpk(float lo, float hi) {
  int r;
  asm("v_cvt_pk_bf16_f32 %0, %1, %2" : "=v"(r) : "v"(lo), "v"(hi));
  return r;
}
static __device__ __forceinline__ void gload_lds16(const ushort* g, ushort* l) {
  __builtin_amdgcn_global_load_lds(
      (const __attribute__((address_space(1))) void*)g,
      (__attribute__((address_space(3))) void*)l, 16, 0, 0);
}

// ---------------------------------------------------------------------------
// Fused convert: inputs -> bf16 AND all 5 weights transposed -> bf16.
// grid: 4704 input blocks + 1440 weight blocks (nx24 x ky12 x wid5).
// ---------------------------------------------------------------------------
__global__ __launch_bounds__(256)
void cvt_all(const float* __restrict__ xq, const float* __restrict__ xk,
             ushort* __restrict__ xqbf, ushort* __restrict__ xkbf,
             const float* __restrict__ Wq, const float* __restrict__ Wkv,
             const float* __restrict__ Wpq, const float* __restrict__ Wproj,
             const float* __restrict__ Wpkv,
             ushort* __restrict__ WqT, ushort* __restrict__ WkvT,
             ushort* __restrict__ WpqT, ushort* __restrict__ WprT,
             ushort* __restrict__ WpkvT, int n4) {
  __shared__ float T[64][65];
  const int blk = blockIdx.x;
  const int tid = threadIdx.x;

  if (blk < 4704) {             // input conversion
    int i = blk*256 + tid;
    const float* src; ushort* dst; int j;
    if (i < n4)        { src = xq; dst = xqbf; j = i; }
    else               { src = xk; dst = xkbf; j = i - n4; }
    float4 v = ((const float4*)src)[j];
    ushort4 o; o.x = f2bf(v.x); o.y = f2bf(v.y); o.z = f2bf(v.z); o.w = f2bf(v.w);
    ((ushort4*)dst)[j] = o;
    return;
  }

  // weight transpose
  int idx = blk - 4704;
  const int wid = idx / 288; idx %= 288;
  const int ky = idx / 24;
  const int nx = idx % 24;
  const float* W; ushort* WT; int N;
  switch (wid) {
    case 0: W = Wq;    WT = WqT;   N = DIM;   break;
    case 1: W = Wkv;   WT = WkvT;  N = 2*DIM; break;
    case 2: W = Wpq;   WT = WpqT;  N = DIM;   break;
    case 3: W = Wproj; WT = WprT;  N = DIM;   break;
    default: W = Wpkv; WT = WpkvT; N = 2*DIM; break;
  }
  if (nx >= N/64) return;
  #pragma unroll
  for (int it = 0; it < 4; it++) {
    int id2 = it*256 + tid;
    int r = id2 >> 4, c4 = (id2 & 15) << 2;
    float4 v = *(const float4*)&W[(size_t)(ky*64 + r)*N + nx*64 + c4];
    T[r][c4+0] = v.x; T[r][c4+1] = v.y; T[r][c4+2] = v.z; T[r][c4+3] = v.w;
  }
  __syncthreads();
  #pragma unroll
  for (int it = 0; it < 4; it++) {
    int id2 = it*256 + tid;
    int n = id2 >> 4, k4 = (id2 & 15) << 2;
    ushort4 o;
    o.x = f2bf(T[k4+0][n]); o.y = f2bf(T[k4+1][n]);
    o.z = f2bf(T[k4+2][n]); o.w = f2bf(T[k4+3][n]);
    *(ushort4*)&WT[(size_t)(nx*64 + n)*DIM + ky*64 + k4] = o;
  }
}

// Vt[(b,f,h)][64][224] bf16, zero-padded n>=196. grid = 192
__global__ __launch_bounds__(256)
void vtrans(const ushort* __restrict__ kvbf, ushort* __restrict__ Vt) {
  __shared__ ushort Vl[NTOK][72];
  const int x = blockIdx.x;
  const int h = x % NH, f = (x / NH) % FR, b = x / (NH*FR);
  const int tid = threadIdx.x;
  for (int idx = tid; idx < NTOK*16; idx += 256) {
    int n = idx >> 4, c4 = (idx & 15) << 2;
    const ushort* p = kvbf + (size_t)(b*SEQ + f*NTOK + n)*(2*DIM) + DIM + h*HD + c4;
    *(ushort4*)&Vl[n][c4] = *(const ushort4*)p;
  }
  __syncthreads();
  ushort* vb = Vt + (size_t)x * (HD*224);
  for (int idx = tid; idx < 64*56; idx += 256) {
    int d = idx / 56, n4 = (idx % 56) << 2;
    ushort4 o;
    o.x = (n4+0 < NTOK) ? Vl[n4+0][d] : (ushort)0;
    o.y = (n4+1 < NTOK) ? Vl[n4+1][d] : (ushort)0;
    o.z = (n4+2 < NTOK) ? Vl[n4+2][d] : (ushort)0;
    o.w = (n4+3 < NTOK) ? Vl[n4+3][d] : (ushort)0;
    *(ushort4*)&vb[(size_t)d*224 + n4] = o;
  }
}

// ---------------------------------------------------------------------------
// Merged q+kv projection, 128x64 tiles. grid (36, 25).
// bx<12: qbf = 0.125*(xq@Wq); else kvbf = xk@Wkv.
// ---------------------------------------------------------------------------
__global__ __launch_bounds__(256)
void proj_pair(const ushort* __restrict__ xqbf, const ushort* __restrict__ xkbf,
               const ushort* __restrict__ WqT, const ushort* __restrict__ WkvT,
               ushort* __restrict__ qbf, ushort* __restrict__ kvbf)
{
  __shared__ ushort As[128][32];
  __shared__ ushort Bs[64][32];
  const int bx = blockIdx.x, by = blockIdx.y;
  const ushort* A; const ushort* Bt; ushort* C; int N, col0; float scale;
  if (bx < 12) { A = xqbf; Bt = WqT;  C = qbf;  N = DIM;   col0 = bx*64;      scale = 0.125f; }
  else         { A = xkbf; Bt = WkvT; C = kvbf; N = 2*DIM; col0 = (bx-12)*64; scale = 1.0f; }

  const int tid = threadIdx.x;
  const int w = tid >> 6, lane = tid & 63;
  const int lq = lane & 15, quad = lane >> 4;
  const int lrow = tid >> 2, lcol = (tid & 3) << 3;

  int ar0 = by*128 + lrow;       if (ar0 > MTOT-1) ar0 = MTOT-1;
  int ar1 = by*128 + 64 + lrow;  if (ar1 > MTOT-1) ar1 = MTOT-1;
  const size_t aoff0 = (size_t)ar0*DIM + lcol;
  const size_t aoff1 = (size_t)ar1*DIM + lcol;
  const size_t boff  = (size_t)(col0 + lrow)*DIM + lcol;

  f32x4 acc[2][4] = {};
  for (int k0 = 0; k0 < DIM; k0 += 32) {
    __syncthreads();
    gload_lds16(A  + aoff0 + k0, &As[w*16][0]);
    gload_lds16(A  + aoff1 + k0, &As[64 + w*16][0]);
    gload_lds16(Bt + boff  + k0, &Bs[w*16][0]);
    __syncthreads();
    s16x8 af[2], bw[4];
    #pragma unroll
    for (int i = 0; i < 2; i++) af[i] = *(const s16x8*)&As[w*32 + i*16 + lq][quad*8];
    #pragma unroll
    for (int j = 0; j < 4; j++) bw[j] = *(const s16x8*)&Bs[j*16 + lq][quad*8];
    #pragma unroll
    for (int i = 0; i < 2; i++)
      #pragma unroll
      for (int j = 0; j < 4; j++)
        acc[i][j] = mfma16(af[i], bw[j], acc[i][j]);
  }

  #pragma unroll
  for (int i = 0; i < 2; i++) {
    #pragma unroll
    for (int r = 0; r < 4; r++) {
      int row = by*128 + w*32 + i*16 + quad*4 + r;
      if (row < MTOT) {
        #pragma unroll
        for (int j = 0; j < 4; j++)
          C[(size_t)row*N + col0 + j*16 + lq] = f2bf(acc[i][j][r] * scale);
      }
    }
  }
}

// ---------------------------------------------------------------------------
// 128x64-tile GEMM for q2diag / outproj. grid (N/64, ceil(M/128)). K=768.
// ---------------------------------------------------------------------------
template<bool BIAS, bool DIAG>
__global__ __launch_bounds__(256)
void gemm64(const ushort* __restrict__ A, const ushort* __restrict__ Bt,
            float* __restrict__ C, const float* __restrict__ bias,
            int M, int N, float scale)
{
  __shared__ ushort As[128][32];
  __shared__ ushort Bs[64][32];
  const int bx = blockIdx.x, by = blockIdx.y;
  const int tid = threadIdx.x;
  const int w = tid >> 6, lane = tid & 63;
  const int lq = lane & 15, quad = lane >> 4;
  const int lrow = tid >> 2, lcol = (tid & 3) << 3;
  const int col0 = bx*64;

  int ar0 = by*128 + lrow;       if (ar0 > M-1) ar0 = M-1;
  int ar1 = by*128 + 64 + lrow;  if (ar1 > M-1) ar1 = M-1;
  size_t aoff0, aoff1;
  if (DIAG) {
    int f0 = (ar0 % SEQ) / NTOK, f1 = (ar1 % SEQ) / NTOK;
    aoff0 = ((size_t)ar0*FR + f0)*DIM + lcol;
    aoff1 = ((size_t)ar1*FR + f1)*DIM + lcol;
  } else {
    aoff0 = (size_t)ar0*DIM + lcol;
    aoff1 = (size_t)ar1*DIM + lcol;
  }
  const size_t boff = (size_t)(col0 + lrow)*DIM + lcol;

  f32x4 acc[2][4] = {};
  for (int k0 = 0; k0 < DIM; k0 += 32) {
    __syncthreads();
    gload_lds16(A  + aoff0 + k0, &As[w*16][0]);
    gload_lds16(A  + aoff1 + k0, &As[64 + w*16][0]);
    gload_lds16(Bt + boff  + k0, &Bs[w*16][0]);
    __syncthreads();
    s16x8 af[2], bw[4];
    #pragma unroll
    for (int i = 0; i < 2; i++) af[i] = *(const s16x8*)&As[w*32 + i*16 + lq][quad*8];
    #pragma unroll
    for (int j = 0; j < 4; j++) bw[j] = *(const s16x8*)&Bs[j*16 + lq][quad*8];
    #pragma unroll
    for (int i = 0; i < 2; i++)
      #pragma unroll
      for (int j = 0; j < 4; j++)
        acc[i][j] = mfma16(af[i], bw[j], acc[i][j]);
  }

  #pragma unroll
  for (int i = 0; i < 2; i++) {
    #pragma unroll
    for (int r = 0; r < 4; r++) {
      int row = by*128 + w*32 + i*16 + quad*4 + r;
      if (row < M) {
        #pragma unroll
        for (int j = 0; j < 4; j++) {
          int col = col0 + j*16 + lq;
          float v = acc[i][j][r] * scale;
          if (BIAS) v += bias[col];
          C[(size_t)row*N + col] = v;
        }
      }
    }
  }
}

// ---------------------------------------------------------------------------
// FUSED stage-2 GEMM pair over x (M2 x 768), 128x128 tiles, m97 staging.
// grid (196 by-major, 6 bx). Replaces the former gemm_big<1> + gemm_big<2>:
// one K-loop stages A once and BOTH WpkvT panels (k-half, v-half), running
// two accumulator sets (acck -> logits, accv -> z). The EPI1->EPI2 dependency
// is block-local: block (by,bx) produces logits exactly for heads {2bx,2bx+1}
// and rows by*128..+127, which is exactly what its softmax+z epilogue needs.
// Logits pass through LDS (no Lg global round-trip).
//  epilogue: p = acck . q2  (shfl-reduce over lq) -> Ls[128][2] in LDS
//            softmax over f (32 threads)          -> attn2 global + a2s
//            z = sum_f a * accv                   -> zo (bf16)
// ---------------------------------------------------------------------------
__global__ __launch_bounds__(256)
void gemm_big_fused(const ushort* __restrict__ A, const ushort* __restrict__ Btk,
                    const ushort* __restrict__ Btv, ushort* __restrict__ zo,
                    const float* __restrict__ q2, float* __restrict__ attn2)
{
  __shared__ ushort As[128][32];
  __shared__ ushort Bks[128][32];
  __shared__ ushort Bvs[128][32];
  __shared__ float  q2s[16][128];
  __shared__ float  Ls[128][2];
  __shared__ float  a2s[16][16];

  const int tid = threadIdx.x;
  const int by = blockIdx.x, bx = blockIdx.y;   // by-major linearization
  const int w = tid >> 6, lane = tid & 63;
  const int lq = lane & 15, quad = lane >> 4;
  const int wr = (w >> 1) * 64, wc = (w & 1) * 64;
  const int hh = wc >> 6;

  const int lrow = tid >> 2, lcol = (tid & 3) << 3;
  const size_t aoff0 = (size_t)(by*128 + lrow)*DIM + lcol;
  const size_t aoff1 = (size_t)(by*128 + 64 + lrow)*DIM + lcol;
  const size_t boff0 = (size_t)(bx*128 + lrow)*DIM + lcol;
  const size_t boff1 = (size_t)(bx*128 + 64 + lrow)*DIM + lcol;

  { // stage q2 tile [16 t-rows][128 cols of this bx]
    int tt = tid >> 4, c0 = (tid & 15) << 3;
    const float* src = q2 + (size_t)(by*16 + tt)*DIM + bx*128 + c0;
    *(float4*)&q2s[tt][c0]     = *(const float4*)src;
    *(float4*)&q2s[tt][c0 + 4] = *(const float4*)(src + 4);
  }

  f32x4 acck[4][4] = {};
  f32x4 accv[4][4] = {};
  for (int k0 = 0; k0 < DIM; k0 += 32) {
    __syncthreads();
    gload_lds16(A   + aoff0 + k0, &As[w*16][0]);
    gload_lds16(A   + aoff1 + k0, &As[64 + w*16][0]);
    gload_lds16(Btk + boff0 + k0, &Bks[w*16][0]);
    gload_lds16(Btk + boff1 + k0, &Bks[64 + w*16][0]);
    gload_lds16(Btv + boff0 + k0, &Bvs[w*16][0]);
    gload_lds16(Btv + boff1 + k0, &Bvs[64 + w*16][0]);
    __syncthreads();
    s16x8 af[4], bk[4], bv[4];
    #pragma unroll
    for (int i = 0; i < 4; i++) af[i] = *(const s16x8*)&As[wr + i*16 + lq][quad*8];
    #pragma unroll
    for (int j = 0; j < 4; j++) {
      bk[j] = *(const s16x8*)&Bks[wc + j*16 + lq][quad*8];
      bv[j] = *(const s16x8*)&Bvs[wc + j*16 + lq][quad*8];
    }
    #pragma unroll
    for (int i = 0; i < 4; i++)
      #pragma unroll
      for (int j = 0; j < 4; j++) {
        acck[i][j] = mfma16(af[i], bk[j], acck[i][j]);
        accv[i][j] = mfma16(af[i], bv[j], accv[i][j]);
      }
  }

  // ---- logits: p[row, head=2bx+hh] = acck . q2s, reduced over 16 lq lanes
  #pragma unroll
  for (int i = 0; i < 4; i++) {
    #pragma unroll
    for (int r = 0; r < 4; r++) {
      int rl = wr + i*16 + quad*4 + r;
      int tt = rl >> 3;
      float p = 0.f;
      #pragma unroll
      for (int j = 0; j < 4; j++)
        p += acck[i][j][r] * q2s[tt][wc + j*16 + lq];
      p += __shfl_xor(p, 1); p += __shfl_xor(p, 2);
      p += __shfl_xor(p, 4); p += __shfl_xor(p, 8);
      if (lq == 0) Ls[rl][hh] = p;
    }
  }
  __syncthreads();

  // ---- softmax over f per (t, hh); write attn2 + a2s
  if (tid < 32) {
    int t = tid >> 1, h2 = tid & 1;
    int gt = by*16 + t, h = bx*2 + h2;
    float v[8], m = -1e30f;
    #pragma unroll
    for (int f = 0; f < 8; f++) {
      v[f] = Ls[t*8 + f][h2];
      m = fmaxf(m, v[f]);
    }
    float sum = 0.f;
    #pragma unroll
    for (int f = 0; f < 8; f++) { v[f] = __expf(v[f] - m); sum += v[f]; }
    float inv = 1.0f / sum;
    int b = gt / SEQ, s = gt % SEQ;
    float* ao = attn2 + ((size_t)(b*NH + h)*SEQ + s)*FR;
    #pragma unroll
    for (int f = 0; f < 8; f++) {
      float a = v[f] * inv;
      ao[f] = a; a2s[t][h2*8 + f] = a;
    }
  }
  __syncthreads();

  // ---- z epilogue from accv
  #pragma unroll
  for (int i = 0; i < 4; i++) {
    float zj[4] = {};
    #pragma unroll
    for (int r = 0; r < 4; r++) {
      int rl = wr + i*16 + quad*4 + r;
      int tt = rl >> 3, f = rl & 7;
      float a = a2s[tt][hh*8 + f];
      #pragma unroll
      for (int j = 0; j < 4; j++) zj[j] += accv[i][j][r] * a;
    }
    #pragma unroll
    for (int j = 0; j < 4; j++) zj[j] += __shfl_xor(zj[j], 16);
    if ((quad & 1) == 0) {
      int tg = by*16 + ((wr + i*16 + quad*4) >> 3);
      #pragma unroll
      for (int j = 0; j < 4; j++) {
        int col = bx*128 + wc + j*16 + lq;
        zo[(size_t)tg*DIM + col] = f2bf(zj[j]);
      }
    }
  }
}

// ---------------------------------------------------------------------------
// Stage 1, 32x32 MFMA, swapped operands (S^T = K.Q^T), in-register P.
// Grid (bh=24, f=8, qt=13): 128 q-rows per block (32/wave).
//  - K [208][64] bf16 in LDS, XOR-swizzled 16B blocks (byte ^= (row&7)<<4),
//    staged via global_load_lds with pre-swizzled global source (rule 21).
//  - QK^T swapped: acc = S^T, each lane owns one q-column -> softmax is
//    per-lane adds + one shfl_xor(32); no max-subtraction (logits bounded, r8).
//  - P^T -> bf16 B-frags in-register: v_cvt_pk_bf16_f32 + v_permlane32_swap
//    (T12). Swap semantics are D.hi <-> S.lo: swap(D=w0,S=w2)/swap(D=w1,S=w3).
//  - PV: X^T = V^T * P^T; Vt[d][224] consumed as A-operand (same global reads).
//  - X normalized by 1/sum at epilogue (per-lane uniform), coalesced store
//    via per-wave LDS transpose through the dead K region.
// ---------------------------------------------------------------------------
__global__ __launch_bounds__(256)
void stage1_mfma(const ushort* __restrict__ qbf, const ushort* __restrict__ kvbf,
                 const ushort* __restrict__ Vt, ushort* __restrict__ x)
{
  __shared__ ushort sh[208*64];   // 26624 B: K tile, then per-wave X transpose

  const int bh = blockIdx.x;   // 0..23
  const int f  = blockIdx.y;   // 0..7
  const int qt = blockIdx.z;   // 0..12
  const int b = bh / NH, h = bh % NH;
  const int tid = threadIdx.x;
  const int w = tid >> 6, lane = tid & 63;
  const int l31 = lane & 31, hl = lane >> 5;

  // ---- K staging: rows 0..191 via global_load_lds (source pre-swizzled so
  //      LDS slot (row, blk16) holds logical column block blk16 ^ (row&7))
  const ushort* kbase = kvbf + ((size_t)b*SEQ + f*NTOK)*(2*DIM) + h*HD;
  #pragma unroll
  for (int p = 0; p < 6; ++p) {
    const int c = w*6 + p;                         // 8-row chunk, rows < 192
    const int row = c*8 + (lane >> 3);
    const ushort* src = kbase + (size_t)row*(2*DIM)
                      + (((lane & 7) ^ (lane >> 3)) << 3);
    gload_lds16(src, &sh[c*512]);
  }
  { // rows 192..207: 192..195 from global, 196..207 zero (same swizzle)
    const int row = 192 + (tid >> 4);
    const int c4  = (tid & 15) << 2;
    ushort4 v; v.x = 0; v.y = 0; v.z = 0; v.w = 0;
    if (row < NTOK)
      v = *(const ushort4*)(kbase + (size_t)row*(2*DIM) + c4);
    *(ushort4*)&sh[row*64 + ((((c4 >> 3) ^ (row & 7)) << 3) | (c4 & 7))] = v;
  }

  // ---- Q fragments (B operand): col = q = l31, k = kk*16 + hl*8 + e
  int qrow = qt*128 + w*32 + l31; if (qrow > SEQ-1) qrow = SEQ-1;
  const ushort* qp = qbf + ((size_t)b*SEQ + qrow)*DIM + h*HD + hl*8;
  const s16x8 bq0 = *(const s16x8*)(qp);
  const s16x8 bq1 = *(const s16x8*)(qp + 16);
  const s16x8 bq2 = *(const s16x8*)(qp + 32);
  const s16x8 bq3 = *(const s16x8*)(qp + 48);

  __syncthreads();

  // ---- S^T = K . Q^T  (acc[nt]: rows n = nt*32 + (r + 8c + 4*hl), col q = l31)
  f32x16 acc[7];
  {
    f32x16 z = {};
    #pragma unroll
    for (int nt = 0; nt < 7; ++nt) acc[nt] = z;
  }
  const int sx = l31 & 7;
  #pragma unroll
  for (int nt = 0; nt < 7; ++nt) {
    const int rl = (nt == 6) ? (l31 & 15) : l31;   // keep tile-6 A-reads in bounds
    const int rbase = (nt*32 + rl)*64;
    acc[nt] = mfma32(*(const s16x8*)&sh[rbase + (((0 + hl) ^ sx) << 3)], bq0, acc[nt]);
    acc[nt] = mfma32(*(const s16x8*)&sh[rbase + (((2 + hl) ^ sx) << 3)], bq1, acc[nt]);
    acc[nt] = mfma32(*(const s16x8*)&sh[rbase + (((4 + hl) ^ sx) << 3)], bq2, acc[nt]);
    acc[nt] = mfma32(*(const s16x8*)&sh[rbase + (((6 + hl) ^ sx) << 3)], bq3, acc[nt]);
  }

  __syncthreads();   // all K reads done -> sh reusable for X transpose

  // ---- softmax (no max-subtraction; logits bounded, validated r8)
  float s0 = 0.f, s1 = 0.f, s2 = 0.f, s3 = 0.f;
  #pragma unroll
  for (int nt = 0; nt < 7; ++nt) {
    #pragma unroll
    for (int g = 0; g < 16; ++g) {
      float e;
      if (nt == 6) {
        if (g < 4) { e = __expf(acc[6][g]); if (hl) e = 0.f; }  // n=192..195 only
        else e = 0.f;
      } else {
        e = __expf(acc[nt][g]);
      }
      acc[nt][g] = e;
      if ((g & 3) == 0) s0 += e; else if ((g & 3) == 1) s1 += e;
      else if ((g & 3) == 2) s2 += e; else s3 += e;
    }
  }
  float sum = (s0 + s1) + (s2 + s3);
  sum += __shfl_xor(sum, 32);
  const float sinv = 1.0f / sum;

  // ---- PV: X^T = V^T . P^T. P^T B-frags built in-register:
  //  w0..w3 = cvt_pk of own acc pairs; permlane32_swap (D.hi <-> S.lo) with
  //  D=w0,S=w2 and D=w1,S=w3 yields all four fragment dwords directly.
  f32x16 o0, o1;
  { f32x16 z = {}; o0 = z; o1 = z; }
  const ushort* vb = Vt + ((size_t)((b*FR + f)*NH + h)) * (HD*224);
  const ushort* vr0 = vb + (size_t)l31*224 + hl*8;
  const ushort* vr1 = vr0 + 32*224;
  #pragma unroll
  for (int nt = 0; nt < 7; ++nt) {
    #pragma unroll
    for (int kh = 0; kh < 2; ++kh) {
      int w0 = cvtpk(acc[nt][8*kh+0], acc[nt][8*kh+1]);   // off kh*16+{0,1} (lo) / {4,5} (hi)
      int w1 = cvtpk(acc[nt][8*kh+2], acc[nt][8*kh+3]);   // off kh*16+{2,3} / {6,7}
      int w2 = cvtpk(acc[nt][8*kh+4], acc[nt][8*kh+5]);   // off kh*16+{8,9} / {12,13}
      int w3 = cvtpk(acc[nt][8*kh+6], acc[nt][8*kh+7]);   // off kh*16+{10,11} / {14,15}
      asm("v_permlane32_swap_b32 %0, %1" : "+v"(w0), "+v"(w2));
      asm("v_permlane32_swap_b32 %0, %1" : "+v"(w1), "+v"(w3));
      union { i32x4 i; s16x8 s; } u;
      u.i.x = w0; u.i.y = w1; u.i.z = w2; u.i.w = w3;     // B dwords e={0,1},{2,3},{4,5},{6,7}
      const int ks = nt*2 + kh;
      const s16x8 va0 = *(const s16x8*)(vr0 + ks*16);
      const s16x8 va1 = *(const s16x8*)(vr1 + ks*16);
      o0 = mfma32(va0, u.s, o0);
      o1 = mfma32(va1, u.s, o1);
    }
  }

  // ---- X store: per-wave transpose 64d x 32q through dead sh region,
  //      XOR-swizzled (phys blk = (d>>3) ^ (q&7)); same-wave only, no barrier.
  ushort* XT = sh + w*2048;
  #pragma unroll
  for (int dt = 0; dt < 2; ++dt) {
    #pragma unroll
    for (int c = 0; c < 4; ++c) {
      #pragma unroll
      for (int rp = 0; rp < 2; ++rp) {
        const float lo = (dt ? o1[4*c + 2*rp]     : o0[4*c + 2*rp])     * sinv;
        const float hi = (dt ? o1[4*c + 2*rp + 1] : o0[4*c + 2*rp + 1]) * sinv;
        const int word = cvtpk(lo, hi);
        const int d = dt*32 + 8*c + 4*hl + 2*rp;
        *(uint*)&XT[l31*64 + (((d >> 3) ^ (l31 & 7)) << 3) + (d & 7)] = (uint)word;
      }
    }
  }
  #pragma unroll
  for (int it = 0; it < 4; ++it) {
    const int q = it*8 + (lane >> 3);
    const int g = lane & 7;
    s16x8 xv = *(const s16x8*)&XT[q*64 + ((g ^ (q & 7)) << 3)];
    const int s = qt*128 + w*32 + q;
    if (s < SEQ) {
      ushort* xp = x + (((size_t)b*SEQ + s)*FR + f)*DIM + h*HD + g*8;
      *(s16x8*)xp = xv;
    }
  }
}

// ---------------------------------------------------------------------------
// Workspace (ushort units; 70.9 MB total; ws >= 95.2 MB proven in round 7):
//  xbf | kvbf (q2 fp32 alias) | qbf (zbf alias) | xqbf (Vt alias) | xkbf
//  WqT | WkvT | WpqT | WprT | WpkvT
// ---------------------------------------------------------------------------
extern "C" void kernel_launch(void* const* d_in, const int* in_sizes, int n_in,
                              void* d_out, int out_size, void* d_ws, size_t ws_size,
                              hipStream_t stream) {
  const float* xq    = (const float*)d_in[0];
  const float* xk    = (const float*)d_in[1];
  const float* Wq    = (const float*)d_in[2];
  const float* Wkv   = (const float*)d_in[3];
  const float* Wpq   = (const float*)d_in[4];
  const float* Wpkv  = (const float*)d_in[5];
  const float* Wproj = (const float*)d_in[6];
  const float* bproj = (const float*)d_in[7];

  float* out   = (float*)d_out;
  float* attn2 = out + (size_t)MTOT*DIM;

  ushort* ws    = (ushort*)d_ws;
  ushort* xbf   = ws;
  ushort* kvbf  = xbf + (size_t)MTOT*FR*DIM;
  float*  q2    = (float*)kvbf;                 // alias, post-stage1
  ushort* qbf   = kvbf + (size_t)MTOT*2*DIM;
  ushort* zbf   = qbf;                          // alias, post-stage1
  ushort* xqbf  = qbf + (size_t)MTOT*DIM;
  ushort* xkbf  = xqbf + (size_t)MTOT*DIM;
  ushort* Vt    = xqbf;                         // alias (dead post-proj)
  ushort* WqT   = xkbf + (size_t)MTOT*DIM;
  ushort* WkvT  = WqT  + (size_t)DIM*DIM;
  ushort* WpqT  = WkvT + (size_t)2*DIM*DIM;
  ushort* WprT  = WpqT + (size_t)DIM*DIM;
  ushort* WpkvT = WprT + (size_t)DIM*DIM;

  dim3 blk(256);
  const int n4 = MTOT*DIM/4;

  cvt_all<<<dim3(4704 + 1440), blk, 0, stream>>>(
      xq, xk, xqbf, xkbf, Wq, Wkv, Wpq, Wproj, Wpkv,
      WqT, WkvT, WpqT, WprT, WpkvT, n4);

  proj_pair<<<dim3(36, (MTOT+127)/128), blk, 0, stream>>>(
      xqbf, xkbf, WqT, WkvT, qbf, kvbf);
  vtrans<<<dim3(BDIM*FR*NH), blk, 0, stream>>>(kvbf, Vt);
  // stage 1: grid (bh, f, qt); blocks sharing K/Vt sit at linear stride 192 = 0 mod 8
  stage1_mfma<<<dim3(BDIM*NH, FR, (SEQ+127)/128), blk, 0, stream>>>(qbf, kvbf, Vt, xbf);
  gemm64<false,true><<<dim3(12, (MTOT+127)/128), blk, 0, stream>>>(
      xbf, WpqT, q2, nullptr, MTOT, DIM, 0.125f);
  gemm_big_fused<<<dim3(M2/128, 6), blk, 0, stream>>>(
      xbf, WpkvT, WpkvT + (size_t)DIM*DIM, zbf, q2, attn2);
  gemm64<true,false><<<dim3(12, (MTOT+127)/128), blk, 0, stream>>>(
      zbf, WprT, out, bproj, MTOT, DIM, 1.0f);
}

// Round 5
// 273.002 us; speedup vs baseline: 1.2728x; 1.2728x over previous
//
#include <hip/hip_runtime.h>

#define BDIM 2
#define SEQ  1568
#define DIM  768
#define NH   12
#define FR   8
#define NTOK 196
#define HD   64
#define MTOT (BDIM*SEQ)   // 3136 token rows
#define M2   (MTOT*FR)    // 25088 (t,f) rows

typedef __attribute__((ext_vector_type(8))) short s16x8;
typedef __attribute__((ext_vector_type(4))) float f32x4;
typedef __attribute__((ext_vector_type(16))) float f32x16;
typedef __attribute__((ext_vector_type(4))) int i32x4;

static __device__ __forceinline__ float bf2f(ushort u) {
  return __uint_as_float(((unsigned)u) << 16);
}
static __device__ __forceinline__ ushort f2bf(float f) {
  unsigned u = __float_as_uint(f);
  unsigned r = (u + 0x7fffu + ((u >> 16) & 1u)) >> 16;
  return (ushort)r;
}
static __device__ __forceinline__ f32x4 mfma16(s16x8 a, s16x8 b, f32x4 c) {
  return __builtin_amdgcn_mfma_f32_16x16x32_bf16(a, b, c, 0, 0, 0);
}
static __device__ __forceinline__ f32x16 mfma32(s16x8 a, s16x8 b, f32x16 c) {
  return __builtin_amdgcn_mfma_f32_32x32x16_bf16(a, b, c, 0, 0, 0);
}
static __device__ __forceinline__ int cvtpk(float lo, float hi) {
  int r;
  asm("v_cvt_pk_bf16_f32 %0, %1, %2" : "=v"(r) : "v"(lo), "v"(hi));
  return r;
}
static __device__ __forceinline__ void gload_lds16(const ushort* g, ushort* l) {
  __builtin_amdgcn_global_load_lds(
      (const __attribute__((address_space(1))) void*)g,
      (__attribute__((address_space(3))) void*)l, 16, 0, 0);
}

// ---------------------------------------------------------------------------
// Fused convert: inputs -> bf16 AND all 5 weights transposed -> bf16.
// grid: 4704 input blocks + 1440 weight blocks (nx24 x ky12 x wid5).
// ---------------------------------------------------------------------------
__global__ __launch_bounds__(256)
void cvt_all(const float* __restrict__ xq, const float* __restrict__ xk,
             ushort* __restrict__ xqbf, ushort* __restrict__ xkbf,
             const float* __restrict__ Wq, const float* __restrict__ Wkv,
             const float* __restrict__ Wpq, const float* __restrict__ Wproj,
             const float* __restrict__ Wpkv,
             ushort* __restrict__ WqT, ushort* __restrict__ WkvT,
             ushort* __restrict__ WpqT, ushort* __restrict__ WprT,
             ushort* __restrict__ WpkvT, int n4) {
  __shared__ float T[64][65];
  const int blk = blockIdx.x;
  const int tid = threadIdx.x;

  if (blk < 4704) {             // input conversion
    int i = blk*256 + tid;
    const float* src; ushort* dst; int j;
    if (i < n4)        { src = xq; dst = xqbf; j = i; }
    else               { src = xk; dst = xkbf; j = i - n4; }
    float4 v = ((const float4*)src)[j];
    ushort4 o; o.x = f2bf(v.x); o.y = f2bf(v.y); o.z = f2bf(v.z); o.w = f2bf(v.w);
    ((ushort4*)dst)[j] = o;
    return;
  }

  // weight transpose
  int idx = blk - 4704;
  const int wid = idx / 288; idx %= 288;
  const int ky = idx / 24;
  const int nx = idx % 24;
  const float* W; ushort* WT; int N;
  switch (wid) {
    case 0: W = Wq;    WT = WqT;   N = DIM;   break;
    case 1: W = Wkv;   WT = WkvT;  N = 2*DIM; break;
    case 2: W = Wpq;   WT = WpqT;  N = DIM;   break;
    case 3: W = Wproj; WT = WprT;  N = DIM;   break;
    default: W = Wpkv; WT = WpkvT; N = 2*DIM; break;
  }
  if (nx >= N/64) return;
  #pragma unroll
  for (int it = 0; it < 4; it++) {
    int id2 = it*256 + tid;
    int r = id2 >> 4, c4 = (id2 & 15) << 2;
    float4 v = *(const float4*)&W[(size_t)(ky*64 + r)*N + nx*64 + c4];
    T[r][c4+0] = v.x; T[r][c4+1] = v.y; T[r][c4+2] = v.z; T[r][c4+3] = v.w;
  }
  __syncthreads();
  #pragma unroll
  for (int it = 0; it < 4; it++) {
    int id2 = it*256 + tid;
    int n = id2 >> 4, k4 = (id2 & 15) << 2;
    ushort4 o;
    o.x = f2bf(T[k4+0][n]); o.y = f2bf(T[k4+1][n]);
    o.z = f2bf(T[k4+2][n]); o.w = f2bf(T[k4+3][n]);
    *(ushort4*)&WT[(size_t)(nx*64 + n)*DIM + ky*64 + k4] = o;
  }
}

// Vt[(b,f,h)][64][224] bf16, zero-padded n>=196. grid = 192
__global__ __launch_bounds__(256)
void vtrans(const ushort* __restrict__ kvbf, ushort* __restrict__ Vt) {
  __shared__ ushort Vl[NTOK][72];
  const int x = blockIdx.x;
  const int h = x % NH, f = (x / NH) % FR, b = x / (NH*FR);
  const int tid = threadIdx.x;
  for (int idx = tid; idx < NTOK*16; idx += 256) {
    int n = idx >> 4, c4 = (idx & 15) << 2;
    const ushort* p = kvbf + (size_t)(b*SEQ + f*NTOK + n)*(2*DIM) + DIM + h*HD + c4;
    *(ushort4*)&Vl[n][c4] = *(const ushort4*)p;
  }
  __syncthreads();
  ushort* vb = Vt + (size_t)x * (HD*224);
  for (int idx = tid; idx < 64*56; idx += 256) {
    int d = idx / 56, n4 = (idx % 56) << 2;
    ushort4 o;
    o.x = (n4+0 < NTOK) ? Vl[n4+0][d] : (ushort)0;
    o.y = (n4+1 < NTOK) ? Vl[n4+1][d] : (ushort)0;
    o.z = (n4+2 < NTOK) ? Vl[n4+2][d] : (ushort)0;
    o.w = (n4+3 < NTOK) ? Vl[n4+3][d] : (ushort)0;
    *(ushort4*)&vb[(size_t)d*224 + n4] = o;
  }
}

// ---------------------------------------------------------------------------
// Merged q+kv projection, 128x64 tiles. grid (36, 25).
// bx<12: qbf = 0.125*(xq@Wq); else kvbf = xk@Wkv.
// ---------------------------------------------------------------------------
__global__ __launch_bounds__(256)
void proj_pair(const ushort* __restrict__ xqbf, const ushort* __restrict__ xkbf,
               const ushort* __restrict__ WqT, const ushort* __restrict__ WkvT,
               ushort* __restrict__ qbf, ushort* __restrict__ kvbf)
{
  __shared__ ushort As[128][32];
  __shared__ ushort Bs[64][32];
  const int bx = blockIdx.x, by = blockIdx.y;
  const ushort* A; const ushort* Bt; ushort* C; int N, col0; float scale;
  if (bx < 12) { A = xqbf; Bt = WqT;  C = qbf;  N = DIM;   col0 = bx*64;      scale = 0.125f; }
  else         { A = xkbf; Bt = WkvT; C = kvbf; N = 2*DIM; col0 = (bx-12)*64; scale = 1.0f; }

  const int tid = threadIdx.x;
  const int w = tid >> 6, lane = tid & 63;
  const int lq = lane & 15, quad = lane >> 4;
  const int lrow = tid >> 2, lcol = (tid & 3) << 3;

  int ar0 = by*128 + lrow;       if (ar0 > MTOT-1) ar0 = MTOT-1;
  int ar1 = by*128 + 64 + lrow;  if (ar1 > MTOT-1) ar1 = MTOT-1;
  const size_t aoff0 = (size_t)ar0*DIM + lcol;
  const size_t aoff1 = (size_t)ar1*DIM + lcol;
  const size_t boff  = (size_t)(col0 + lrow)*DIM + lcol;

  f32x4 acc[2][4] = {};
  for (int k0 = 0; k0 < DIM; k0 += 32) {
    __syncthreads();
    gload_lds16(A  + aoff0 + k0, &As[w*16][0]);
    gload_lds16(A  + aoff1 + k0, &As[64 + w*16][0]);
    gload_lds16(Bt + boff  + k0, &Bs[w*16][0]);
    __syncthreads();
    s16x8 af[2], bw[4];
    #pragma unroll
    for (int i = 0; i < 2; i++) af[i] = *(const s16x8*)&As[w*32 + i*16 + lq][quad*8];
    #pragma unroll
    for (int j = 0; j < 4; j++) bw[j] = *(const s16x8*)&Bs[j*16 + lq][quad*8];
    #pragma unroll
    for (int i = 0; i < 2; i++)
      #pragma unroll
      for (int j = 0; j < 4; j++)
        acc[i][j] = mfma16(af[i], bw[j], acc[i][j]);
  }

  #pragma unroll
  for (int i = 0; i < 2; i++) {
    #pragma unroll
    for (int r = 0; r < 4; r++) {
      int row = by*128 + w*32 + i*16 + quad*4 + r;
      if (row < MTOT) {
        #pragma unroll
        for (int j = 0; j < 4; j++)
          C[(size_t)row*N + col0 + j*16 + lq] = f2bf(acc[i][j][r] * scale);
      }
    }
  }
}

// ---------------------------------------------------------------------------
// 128x64-tile GEMM for q2diag / z / outproj. grid (N/64, ceil(M/128)). K=768.
// BF16OUT: C is ushort bf16; else float.
// ---------------------------------------------------------------------------
template<bool BIAS, bool DIAG, bool BF16OUT>
__global__ __launch_bounds__(256)
void gemm64(const ushort* __restrict__ A, const ushort* __restrict__ Bt,
            void* __restrict__ Cv, const float* __restrict__ bias,
            int M, int N, float scale)
{
  __shared__ ushort As[128][32];
  __shared__ ushort Bs[64][32];
  const int bx = blockIdx.x, by = blockIdx.y;
  const int tid = threadIdx.x;
  const int w = tid >> 6, lane = tid & 63;
  const int lq = lane & 15, quad = lane >> 4;
  const int lrow = tid >> 2, lcol = (tid & 3) << 3;
  const int col0 = bx*64;

  int ar0 = by*128 + lrow;       if (ar0 > M-1) ar0 = M-1;
  int ar1 = by*128 + 64 + lrow;  if (ar1 > M-1) ar1 = M-1;
  size_t aoff0, aoff1;
  if (DIAG) {
    int f0 = (ar0 % SEQ) / NTOK, f1 = (ar1 % SEQ) / NTOK;
    aoff0 = ((size_t)ar0*FR + f0)*DIM + lcol;
    aoff1 = ((size_t)ar1*FR + f1)*DIM + lcol;
  } else {
    aoff0 = (size_t)ar0*DIM + lcol;
    aoff1 = (size_t)ar1*DIM + lcol;
  }
  const size_t boff = (size_t)(col0 + lrow)*DIM + lcol;

  f32x4 acc[2][4] = {};
  for (int k0 = 0; k0 < DIM; k0 += 32) {
    __syncthreads();
    gload_lds16(A  + aoff0 + k0, &As[w*16][0]);
    gload_lds16(A  + aoff1 + k0, &As[64 + w*16][0]);
    gload_lds16(Bt + boff  + k0, &Bs[w*16][0]);
    __syncthreads();
    s16x8 af[2], bw[4];
    #pragma unroll
    for (int i = 0; i < 2; i++) af[i] = *(const s16x8*)&As[w*32 + i*16 + lq][quad*8];
    #pragma unroll
    for (int j = 0; j < 4; j++) bw[j] = *(const s16x8*)&Bs[j*16 + lq][quad*8];
    #pragma unroll
    for (int i = 0; i < 2; i++)
      #pragma unroll
      for (int j = 0; j < 4; j++)
        acc[i][j] = mfma16(af[i], bw[j], acc[i][j]);
  }

  #pragma unroll
  for (int i = 0; i < 2; i++) {
    #pragma unroll
    for (int r = 0; r < 4; r++) {
      int row = by*128 + w*32 + i*16 + quad*4 + r;
      if (row < M) {
        #pragma unroll
        for (int j = 0; j < 4; j++) {
          int col = col0 + j*16 + lq;
          float v = acc[i][j][r] * scale;
          if (BIAS) v += bias[col];
          if (BF16OUT) ((ushort*)Cv)[(size_t)row*N + col] = f2bf(v);
          else         ((float*)Cv)[(size_t)row*N + col] = v;
        }
      }
    }
  }
}

// ---------------------------------------------------------------------------
// Logits GEMM over x (M2 x 768), 128x128 tiles, m97 staging (R2-proven).
// grid (196 by-major, 6 bx).
// epilogue: Lg[row*12 + head] = sum_col D[row][col] * q2[t][col]
// ---------------------------------------------------------------------------
__global__ __launch_bounds__(256)
void gemm_logits(const ushort* __restrict__ A, const ushort* __restrict__ Bt,
                 float* __restrict__ Lg, const float* __restrict__ q2)
{
  __shared__ ushort As[128][32];
  __shared__ ushort Bs[128][32];
  __shared__ float  q2s[16][128];

  const int tid = threadIdx.x;
  const int by = blockIdx.x, bx = blockIdx.y;   // by-major linearization
  const int w = tid >> 6, lane = tid & 63;
  const int lq = lane & 15, quad = lane >> 4;
  const int wr = (w >> 1) * 64, wc = (w & 1) * 64;

  const int lrow = tid >> 2, lcol = (tid & 3) << 3;
  const size_t aoff0 = (size_t)(by*128 + lrow)*DIM + lcol;
  const size_t aoff1 = (size_t)(by*128 + 64 + lrow)*DIM + lcol;
  const size_t boff0 = (size_t)(bx*128 + lrow)*DIM + lcol;
  const size_t boff1 = (size_t)(bx*128 + 64 + lrow)*DIM + lcol;

  { // stage q2 tile [16 t-rows][128 cols of this bx]
    int tt = tid >> 4, c0 = (tid & 15) << 3;
    const float* src = q2 + (size_t)(by*16 + tt)*DIM + bx*128 + c0;
    *(float4*)&q2s[tt][c0]     = *(const float4*)src;
    *(float4*)&q2s[tt][c0 + 4] = *(const float4*)(src + 4);
  }

  f32x4 acc[4][4] = {};
  for (int k0 = 0; k0 < DIM; k0 += 32) {
    __syncthreads();
    gload_lds16(A  + aoff0 + k0, &As[w*16][0]);
    gload_lds16(A  + aoff1 + k0, &As[64 + w*16][0]);
    gload_lds16(Bt + boff0 + k0, &Bs[w*16][0]);
    gload_lds16(Bt + boff1 + k0, &Bs[64 + w*16][0]);
    __syncthreads();
    s16x8 af[4], bw[4];
    #pragma unroll
    for (int i = 0; i < 4; i++) af[i] = *(const s16x8*)&As[wr + i*16 + lq][quad*8];
    #pragma unroll
    for (int j = 0; j < 4; j++) bw[j] = *(const s16x8*)&Bs[wc + j*16 + lq][quad*8];
    #pragma unroll
    for (int i = 0; i < 4; i++)
      #pragma unroll
      for (int j = 0; j < 4; j++)
        acc[i][j] = mfma16(af[i], bw[j], acc[i][j]);
  }

  const int head = bx*2 + (wc >> 6);
  #pragma unroll
  for (int i = 0; i < 4; i++) {
    #pragma unroll
    for (int r = 0; r < 4; r++) {
      int rl = wr + i*16 + quad*4 + r;
      int tt = rl >> 3;
      float p = 0.f;
      #pragma unroll
      for (int j = 0; j < 4; j++)
        p += acc[i][j][r] * q2s[tt][wc + j*16 + lq];
      p += __shfl_xor(p, 1); p += __shfl_xor(p, 2);
      p += __shfl_xor(p, 4); p += __shfl_xor(p, 8);
      if (lq == 0)
        Lg[(size_t)(by*128 + rl)*NH + head] = p;
    }
  }
}

// ---------------------------------------------------------------------------
// Softmax over f + x-aggregation. grid 98 (32 t each), 256 threads.
//  attn2[b,h,s,f] = softmax_f(Lg[(t,f),h]);  xa[t,col] = sum_f a[t,h(col),f]*x[(t,f),col]
// Replaces the 29.6-GFLOP v2 GEMM: z = xa @ Wpv (3.7 GFLOP) follows.
// ---------------------------------------------------------------------------
__global__ __launch_bounds__(256)
void softagg(const float* __restrict__ Lg, const ushort* __restrict__ x,
             float* __restrict__ attn2, ushort* __restrict__ xa)
{
  __shared__ float as[32][NH][FR];   // 12 KB
  const int t0 = blockIdx.x * 32;
  const int tid = threadIdx.x;

  for (int idx = tid; idx < 32*NH; idx += 256) {
    int tl = idx / NH, h = idx % NH;
    int gt = t0 + tl;
    const float* lp = Lg + (size_t)(gt*FR)*NH + h;   // f-stride NH
    float v[FR], m = -1e30f;
    #pragma unroll
    for (int f = 0; f < FR; f++) { v[f] = lp[f*NH]; m = fmaxf(m, v[f]); }
    float s = 0.f;
    #pragma unroll
    for (int f = 0; f < FR; f++) { v[f] = __expf(v[f] - m); s += v[f]; }
    float inv = 1.0f / s;
    int b = gt / SEQ, sI = gt % SEQ;
    float* ao = attn2 + ((size_t)(b*NH + h)*SEQ + sI)*FR;
    #pragma unroll
    for (int f = 0; f < FR; f++) {
      float a = v[f] * inv;
      ao[f] = a; as[tl][h][f] = a;
    }
  }
  __syncthreads();

  for (int idx = tid; idx < 32*96; idx += 256) {
    int tl = idx / 96, c8 = idx % 96;
    int gt = t0 + tl;
    int col = c8*8, h = col >> 6;
    const ushort* xp = x + ((size_t)gt*FR)*DIM + col;
    float av[8] = {};
    #pragma unroll
    for (int f = 0; f < FR; f++) {
      float a = as[tl][h][f];
      s16x8 xv = *(const s16x8*)(xp + (size_t)f*DIM);
      #pragma unroll
      for (int e = 0; e < 8; e++) av[e] += a * bf2f((ushort)xv[e]);
    }
    ushort4 o0, o1;
    o0.x = f2bf(av[0]); o0.y = f2bf(av[1]); o0.z = f2bf(av[2]); o0.w = f2bf(av[3]);
    o1.x = f2bf(av[4]); o1.y = f2bf(av[5]); o1.z = f2bf(av[6]); o1.w = f2bf(av[7]);
    ushort* op = xa + (size_t)gt*DIM + col;
    *(ushort4*)op = o0; *(ushort4*)(op + 4) = o1;
  }
}

// ---------------------------------------------------------------------------
// Stage 1, 32x32 MFMA, swapped operands (S^T = K.Q^T), in-register P.
// Grid (bh=24, f=8, qt=13): 128 q-rows per block (32/wave).
//  - K [208][64] bf16 in LDS, XOR-swizzled 16B blocks (byte ^= (row&7)<<4),
//    staged via global_load_lds with pre-swizzled global source (rule 21).
//  - QK^T swapped: acc = S^T, each lane owns one q-column -> softmax is
//    per-lane adds + one shfl_xor(32); no max-subtraction (logits bounded, r8).
//  - P^T -> bf16 B-frags in-register: v_cvt_pk_bf16_f32 + v_permlane32_swap
//    (T12). Swap semantics are D.hi <-> S.lo: swap(D=w0,S=w2)/swap(D=w1,S=w3).
//  - PV: X^T = V^T * P^T; Vt[d][224] consumed as A-operand (same global reads).
//  - X normalized by 1/sum at epilogue (per-lane uniform), coalesced store
//    via per-wave LDS transpose through the dead K region.
// ---------------------------------------------------------------------------
__global__ __launch_bounds__(256)
void stage1_mfma(const ushort* __restrict__ qbf, const ushort* __restrict__ kvbf,
                 const ushort* __restrict__ Vt, ushort* __restrict__ x)
{
  __shared__ ushort sh[208*64];   // 26624 B: K tile, then per-wave X transpose

  const int bh = blockIdx.x;   // 0..23
  const int f  = blockIdx.y;   // 0..7
  const int qt = blockIdx.z;   // 0..12
  const int b = bh / NH, h = bh % NH;
  const int tid = threadIdx.x;
  const int w = tid >> 6, lane = tid & 63;
  const int l31 = lane & 31, hl = lane >> 5;

  // ---- K staging: rows 0..191 via global_load_lds (source pre-swizzled so
  //      LDS slot (row, blk16) holds logical column block blk16 ^ (row&7))
  const ushort* kbase = kvbf + ((size_t)b*SEQ + f*NTOK)*(2*DIM) + h*HD;
  #pragma unroll
  for (int p = 0; p < 6; ++p) {
    const int c = w*6 + p;                         // 8-row chunk, rows < 192
    const int row = c*8 + (lane >> 3);
    const ushort* src = kbase + (size_t)row*(2*DIM)
                      + (((lane & 7) ^ (lane >> 3)) << 3);
    gload_lds16(src, &sh[c*512]);
  }
  { // rows 192..207: 192..195 from global, 196..207 zero (same swizzle)
    const int row = 192 + (tid >> 4);
    const int c4  = (tid & 15) << 2;
    ushort4 v; v.x = 0; v.y = 0; v.z = 0; v.w = 0;
    if (row < NTOK)
      v = *(const ushort4*)(kbase + (size_t)row*(2*DIM) + c4);
    *(ushort4*)&sh[row*64 + ((((c4 >> 3) ^ (row & 7)) << 3) | (c4 & 7))] = v;
  }

  // ---- Q fragments (B operand): col = q = l31, k = kk*16 + hl*8 + e
  int qrow = qt*128 + w*32 + l31; if (qrow > SEQ-1) qrow = SEQ-1;
  const ushort* qp = qbf + ((size_t)b*SEQ + qrow)*DIM + h*HD + hl*8;
  const s16x8 bq0 = *(const s16x8*)(qp);
  const s16x8 bq1 = *(const s16x8*)(qp + 16);
  const s16x8 bq2 = *(const s16x8*)(qp + 32);
  const s16x8 bq3 = *(const s16x8*)(qp + 48);

  __syncthreads();

  // ---- S^T = K . Q^T  (acc[nt]: rows n = nt*32 + (r + 8c + 4*hl), col q = l31)
  f32x16 acc[7];
  {
    f32x16 z = {};
    #pragma unroll
    for (int nt = 0; nt < 7; ++nt) acc[nt] = z;
  }
  const int sx = l31 & 7;
  #pragma unroll
  for (int nt = 0; nt < 7; ++nt) {
    const int rl = (nt == 6) ? (l31 & 15) : l31;   // keep tile-6 A-reads in bounds
    const int rbase = (nt*32 + rl)*64;
    acc[nt] = mfma32(*(const s16x8*)&sh[rbase + (((0 + hl) ^ sx) << 3)], bq0, acc[nt]);
    acc[nt] = mfma32(*(const s16x8*)&sh[rbase + (((2 + hl) ^ sx) << 3)], bq1, acc[nt]);
    acc[nt] = mfma32(*(const s16x8*)&sh[rbase + (((4 + hl) ^ sx) << 3)], bq2, acc[nt]);
    acc[nt] = mfma32(*(const s16x8*)&sh[rbase + (((6 + hl) ^ sx) << 3)], bq3, acc[nt]);
  }

  __syncthreads();   // all K reads done -> sh reusable for X transpose

  // ---- softmax (no max-subtraction; logits bounded, validated r8)
  float s0 = 0.f, s1 = 0.f, s2 = 0.f, s3 = 0.f;
  #pragma unroll
  for (int nt = 0; nt < 7; ++nt) {
    #pragma unroll
    for (int g = 0; g < 16; ++g) {
      float e;
      if (nt == 6) {
        if (g < 4) { e = __expf(acc[6][g]); if (hl) e = 0.f; }  // n=192..195 only
        else e = 0.f;
      } else {
        e = __expf(acc[nt][g]);
      }
      acc[nt][g] = e;
      if ((g & 3) == 0) s0 += e; else if ((g & 3) == 1) s1 += e;
      else if ((g & 3) == 2) s2 += e; else s3 += e;
    }
  }
  float sum = (s0 + s1) + (s2 + s3);
  sum += __shfl_xor(sum, 32);
  const float sinv = 1.0f / sum;

  // ---- PV: X^T = V^T . P^T. P^T B-frags built in-register:
  //  w0..w3 = cvt_pk of own acc pairs; permlane32_swap (D.hi <-> S.lo) with
  //  D=w0,S=w2 and D=w1,S=w3 yields all four fragment dwords directly.
  f32x16 o0, o1;
  { f32x16 z = {}; o0 = z; o1 = z; }
  const ushort* vb = Vt + ((size_t)((b*FR + f)*NH + h)) * (HD*224);
  const ushort* vr0 = vb + (size_t)l31*224 + hl*8;
  const ushort* vr1 = vr0 + 32*224;
  #pragma unroll
  for (int nt = 0; nt < 7; ++nt) {
    #pragma unroll
    for (int kh = 0; kh < 2; ++kh) {
      int w0 = cvtpk(acc[nt][8*kh+0], acc[nt][8*kh+1]);   // off kh*16+{0,1} (lo) / {4,5} (hi)
      int w1 = cvtpk(acc[nt][8*kh+2], acc[nt][8*kh+3]);   // off kh*16+{2,3} / {6,7}
      int w2 = cvtpk(acc[nt][8*kh+4], acc[nt][8*kh+5]);   // off kh*16+{8,9} / {12,13}
      int w3 = cvtpk(acc[nt][8*kh+6], acc[nt][8*kh+7]);   // off kh*16+{10,11} / {14,15}
      asm("v_permlane32_swap_b32 %0, %1" : "+v"(w0), "+v"(w2));
      asm("v_permlane32_swap_b32 %0, %1" : "+v"(w1), "+v"(w3));
      union { i32x4 i; s16x8 s; } u;
      u.i.x = w0; u.i.y = w1; u.i.z = w2; u.i.w = w3;     // B dwords e={0,1},{2,3},{4,5},{6,7}
      const int ks = nt*2 + kh;
      const s16x8 va0 = *(const s16x8*)(vr0 + ks*16);
      const s16x8 va1 = *(const s16x8*)(vr1 + ks*16);
      o0 = mfma32(va0, u.s, o0);
      o1 = mfma32(va1, u.s, o1);
    }
  }

  // ---- X store: per-wave transpose 64d x 32q through dead sh region,
  //      XOR-swizzled (phys blk = (d>>3) ^ (q&7)); same-wave only, no barrier.
  ushort* XT = sh + w*2048;
  #pragma unroll
  for (int dt = 0; dt < 2; ++dt) {
    #pragma unroll
    for (int c = 0; c < 4; ++c) {
      #pragma unroll
      for (int rp = 0; rp < 2; ++rp) {
        const float lo = (dt ? o1[4*c + 2*rp]     : o0[4*c + 2*rp])     * sinv;
        const float hi = (dt ? o1[4*c + 2*rp + 1] : o0[4*c + 2*rp + 1]) * sinv;
        const int word = cvtpk(lo, hi);
        const int d = dt*32 + 8*c + 4*hl + 2*rp;
        *(uint*)&XT[l31*64 + (((d >> 3) ^ (l31 & 7)) << 3) + (d & 7)] = (uint)word;
      }
    }
  }
  #pragma unroll
  for (int it = 0; it < 4; ++it) {
    const int q = it*8 + (lane >> 3);
    const int g = lane & 7;
    s16x8 xv = *(const s16x8*)&XT[q*64 + ((g ^ (q & 7)) << 3)];
    const int s = qt*128 + w*32 + q;
    if (s < SEQ) {
      ushort* xp = x + (((size_t)b*SEQ + s)*FR + f)*DIM + h*HD + g*8;
      *(s16x8*)xp = xv;
    }
  }
}

// ---------------------------------------------------------------------------
// Workspace (ushort units; ~70.9 MB total; ws >= 95.2 MB proven in round 7):
//  xbf | kvbf (q2 fp32 alias) | qbf (zbf alias) | xqbf (Vt / Lg alias) |
//  xkbf (xa alias) | WqT | WkvT | WpqT | WprT | WpkvT
// ---------------------------------------------------------------------------
extern "C" void kernel_launch(void* const* d_in, const int* in_sizes, int n_in,
                              void* d_out, int out_size, void* d_ws, size_t ws_size,
                              hipStream_t stream) {
  const float* xq    = (const float*)d_in[0];
  const float* xk    = (const float*)d_in[1];
  const float* Wq    = (const float*)d_in[2];
  const float* Wkv   = (const float*)d_in[3];
  const float* Wpq   = (const float*)d_in[4];
  const float* Wpkv  = (const float*)d_in[5];
  const float* Wproj = (const float*)d_in[6];
  const float* bproj = (const float*)d_in[7];

  float* out   = (float*)d_out;
  float* attn2 = out + (size_t)MTOT*DIM;

  ushort* ws    = (ushort*)d_ws;
  ushort* xbf   = ws;
  ushort* kvbf  = xbf + (size_t)MTOT*FR*DIM;
  float*  q2    = (float*)kvbf;                 // alias, post-stage1
  ushort* qbf   = kvbf + (size_t)MTOT*2*DIM;
  ushort* zbf   = qbf;                          // alias, post-stage1
  ushort* xqbf  = qbf + (size_t)MTOT*DIM;
  ushort* xkbf  = xqbf + (size_t)MTOT*DIM;
  ushort* Vt    = xqbf;                         // alias (dead post-proj)
  float*  Lg    = (float*)xqbf;                 // alias (post-stage1)
  ushort* xa    = xkbf;                         // alias (dead post-proj)
  ushort* WqT   = xkbf + (size_t)MTOT*DIM;
  ushort* WkvT  = WqT  + (size_t)DIM*DIM;
  ushort* WpqT  = WkvT + (size_t)2*DIM*DIM;
  ushort* WprT  = WpqT + (size_t)DIM*DIM;
  ushort* WpkvT = WprT + (size_t)DIM*DIM;

  dim3 blk(256);
  const int n4 = MTOT*DIM/4;

  cvt_all<<<dim3(4704 + 1440), blk, 0, stream>>>(
      xq, xk, xqbf, xkbf, Wq, Wkv, Wpq, Wproj, Wpkv,
      WqT, WkvT, WpqT, WprT, WpkvT, n4);

  proj_pair<<<dim3(36, (MTOT+127)/128), blk, 0, stream>>>(
      xqbf, xkbf, WqT, WkvT, qbf, kvbf);
  vtrans<<<dim3(BDIM*FR*NH), blk, 0, stream>>>(kvbf, Vt);
  // stage 1: grid (bh, f, qt); blocks sharing K/Vt sit at linear stride 192 = 0 mod 8
  stage1_mfma<<<dim3(BDIM*NH, FR, (SEQ+127)/128), blk, 0, stream>>>(qbf, kvbf, Vt, xbf);
  gemm64<false,true,false><<<dim3(12, (MTOT+127)/128), blk, 0, stream>>>(
      xbf, WpqT, q2, nullptr, MTOT, DIM, 0.125f);
  gemm_logits<<<dim3(M2/128, 6), blk, 0, stream>>>(xbf, WpkvT, Lg, q2);
  softagg<<<dim3(MTOT/32), blk, 0, stream>>>(Lg, xbf, attn2, xa);
  gemm64<false,false,true><<<dim3(12, (MTOT+127)/128), blk, 0, stream>>>(
      xa, WpkvT + (size_t)DIM*DIM, zbf, nullptr, MTOT, DIM, 1.0f);
  gemm64<true,false,false><<<dim3(12, (MTOT+127)/128), blk, 0, stream>>>(
      zbf, WprT, out, bproj, MTOT, DIM, 1.0f);
}